// Round 3
// baseline (86.724 us; speedup 1.0000x reference)
//
#include <hip/hip_runtime.h>

// Shape fixed by reference setup_inputs(): B=256, L=512, D=64, fp32.
constexpr int Bn = 256;
constexpr int Ln = 512;
constexpr int Dn = 64;
constexpr int HALF = Ln / 2;   // rows per partial block
constexpr float EPS_LOG = 1e-7f;
constexpr float EPS_COS = 1e-8f;

// Only wnl[b,b] is consumed by the reference, so per sample we need just one
// cosine row: cos(emb[b,b,:], emb[b,k,:]) for k in [0,512).
//
// K1: grid = 512 (2 blocks per sample, one half of the k-range each),
// 1024 threads = 16 waves -> 2 blocks/CU = 32 waves/CU (full occupancy;
// __launch_bounds__(1024,8) caps VGPRs at 64). Each 16-lane subgroup owns one
// row k, lane i holding float4 emb[b][k][4i..4i+3]; a wave's 4 subgroups cover
// 4 consecutive rows = one contiguous 1 KB burst. Labels are read as scalar
// broadcast global loads (no LDS staging -> no barrier in the hot path).
// Partials combine in d_ws: atomicMax (float-as-uint, all values >= 0),
// atomicAdd for the log-sums.
//
// ws layout (floats): [0..255] per-sample row-max (uint bits),
//                     [256..511] per-sample LN = sum log(1-(p+eps)),
//                     [512] P = total sum labels*log(p+eps).
__global__ __launch_bounds__(1024, 8) void wnl_part(
    const float* __restrict__ emb,     // (B, L, D)
    const float* __restrict__ probs,   // (B, L)
    const float* __restrict__ labels,  // (B, L)
    float* __restrict__ ws)
{
    const int g    = blockIdx.x;       // 0..511
    const int b    = g >> 1;           // sample
    const int h    = g & 1;            // which half of the k-range
    const int tid  = threadIdx.x;
    const int wave = tid >> 6;         // 0..15
    const int lane = tid & 63;
    const int sub  = lane >> 4;        // row within the wave's 4-row group
    const int i16  = lane & 15;        // float4 chunk of D
    constexpr int NW = 16;

    const float* eb = emb    + (size_t)b * Ln * Dn;
    const float* pb = probs  + (size_t)b * Ln;
    const float* lb = labels + (size_t)b * Ln;

    // q = emb[b, b, :]  (b < 256 <= L); 16B chunk per lane, broadcast across subs
    const float4 qv = *(const float4*)(eb + (size_t)b * Dn + 4 * i16);
    float nq = qv.x * qv.x + qv.y * qv.y + qv.z * qv.z + qv.w * qv.w;
    #pragma unroll
    for (int off = 1; off < 16; off <<= 1) nq += __shfl_xor(nq, off);
    const float norm_q = sqrtf(nq);

    // 256 rows / (16 waves * 4 rows) = 4 unrolled iterations
    float maxv = 0.f;
    #pragma unroll
    for (int it = 0; it < HALF / (NW * 4); ++it) {
        const int k = h * HALF + it * (NW * 4) + wave * 4 + sub;
        const float4 v = *(const float4*)(eb + (size_t)k * Dn + 4 * i16);
        const float lk = lb[k];        // same addr across 16 lanes -> broadcast
        float d = qv.x * v.x + qv.y * v.y + qv.z * v.z + qv.w * v.w;
        float n = v.x * v.x + v.y * v.y + v.z * v.z + v.w * v.w;
        #pragma unroll
        for (int off = 1; off < 16; off <<= 1) {
            d += __shfl_xor(d, off);
            n += __shfl_xor(n, off);
        }
        float denom = fmaxf(norm_q * sqrtf(n), EPS_COS);
        float m     = fmaxf(__fdividef(d, denom), 0.f) * lk;  // relu, mask
        maxv = fmaxf(maxv, m);
    }
    maxv = fmaxf(maxv, __shfl_xor(maxv, 16));
    maxv = fmaxf(maxv, __shfl_xor(maxv, 32));

    // This block's half of the prob sums (256 elements -> waves 0..3)
    float pos = 0.f, lng = 0.f;
    if (tid < HALF) {
        const int l = h * HALF + tid;
        float p = pb[l] + EPS_LOG;
        pos = lb[l] * __logf(p);
        lng = __logf(1.f - p);
    }
    #pragma unroll
    for (int off = 32; off; off >>= 1) {
        pos += __shfl_xor(pos, off);
        lng += __shfl_xor(lng, off);
    }

    __shared__ float s_max[NW], s_pos[NW], s_lng[NW];
    if (lane == 0) { s_max[wave] = maxv; s_pos[wave] = pos; s_lng[wave] = lng; }
    __syncthreads();

    if (tid == 0) {
        float rm = 0.f, P = 0.f, LN = 0.f;
        #pragma unroll
        for (int w = 0; w < NW; ++w) {
            rm = fmaxf(rm, s_max[w]);
            P += s_pos[w];
            LN += s_lng[w];
        }
        atomicMax((unsigned int*)(ws + b), __float_as_uint(rm));  // values >= 0
        atomicAdd(ws + Bn + b, LN);
        atomicAdd(ws + 2 * Bn, P);
    }
}

// K2: single block combines the 256 per-sample partials and writes the scalar.
__global__ __launch_bounds__(256) void wnl_final(
    const float* __restrict__ labels,
    const float* __restrict__ ws,
    float* __restrict__ out)
{
    const int b    = threadIdx.x;      // 0..255 = sample
    const int wave = b >> 6, lane = b & 63;

    float mx = __uint_as_float(((const unsigned int*)ws)[b]);
    float ln = ws[Bn + b];
    // weak-negative weight only if labels[b,b] == 0
    float t  = (labels[(size_t)b * Ln + b] == 0.f) ? mx * ln : 0.f;

    #pragma unroll
    for (int off = 32; off; off >>= 1) t += __shfl_xor(t, off);

    __shared__ float s[4];
    if (lane == 0) s[wave] = t;
    __syncthreads();

    if (b == 0) {
        float T = s[0] + s[1] + s[2] + s[3];
        float P = ws[2 * Bn];
        out[0] = (-P - T) * (1.f / (float)Bn);
    }
}

extern "C" void kernel_launch(void* const* d_in, const int* in_sizes, int n_in,
                              void* d_out, int out_size, void* d_ws, size_t ws_size,
                              hipStream_t stream) {
    const float* emb    = (const float*)d_in[0];
    const float* probs  = (const float*)d_in[1];
    const float* labels = (const float*)d_in[2];
    float* ws  = (float*)d_ws;
    float* out = (float*)d_out;

    // d_ws is poisoned 0xAA before every timed launch; zero the bit we use
    // (atomics accumulate into it). d_out is written directly by wnl_final.
    hipMemsetAsync(ws, 0, (2 * Bn + 1) * sizeof(float), stream);
    wnl_part<<<2 * Bn, 1024, 0, stream>>>(emb, probs, labels, ws);
    wnl_final<<<1, 256, 0, stream>>>(labels, ws, out);
}

// Round 4
// 77.577 us; speedup vs baseline: 1.1179x; 1.1179x over previous
//
#include <hip/hip_runtime.h>

// Shape fixed by reference setup_inputs(): B=256, L=512, D=64, fp32.
constexpr int Bn = 256;
constexpr int Ln = 512;
constexpr int Dn = 64;
constexpr float EPS_LOG = 1e-7f;
constexpr float EPS_COS = 1e-8f;

// Reference only consumes wnl[b,b] (the diagonal), so per sample we need just
// one cosine row: cos(emb[b,b,:], emb[b,k,:]) for k in [0,512).
//
// K1: one block per sample (grid=256 -> 1 block/CU), 1024 threads = 16 waves.
// Each 16-lane subgroup owns one row k; lane i holds float4 emb[b][k][4i..].
// A wave's 4 subgroups cover 4 consecutive rows = one contiguous 1 KB burst.
// 8 fully-unrolled independent iterations per wave keep 8 KB of loads in
// flight. Labels come from global broadcast loads (2 KB, L1-hit after first
// touch) -- no LDS staging, no barrier in the hot path (R2 had a cross-wave
// race on its LDS label array; this removes it).
// Result: ONE plain store per sample into ws[b] (no memset, no atomics):
//   ws[b] = -P_b - wnl_b * LN_b
// K2: a single 64-lane wave float4-loads the 256 partials, shuffle-reduces,
// and writes out[0] = sum / B. Poisoned d_ws/d_out are never read before
// being overwritten, so no init pass is needed.
__global__ __launch_bounds__(1024) void wnl_part(
    const float* __restrict__ emb,     // (B, L, D)
    const float* __restrict__ probs,   // (B, L)
    const float* __restrict__ labels,  // (B, L)
    float* __restrict__ ws)            // >= Bn floats
{
    const int b    = blockIdx.x;
    const int tid  = threadIdx.x;
    const int wave = tid >> 6;         // 0..15
    const int lane = tid & 63;
    const int sub  = lane >> 4;        // row within the wave's 4-row group
    const int i16  = lane & 15;        // float4 chunk of D
    constexpr int NW = 16;

    const float* eb = emb    + (size_t)b * Ln * Dn;
    const float* pb = probs  + (size_t)b * Ln;
    const float* lb = labels + (size_t)b * Ln;

    // q = emb[b, b, :] (b < 256 <= L); 16 B per lane, broadcast across subgroups
    const float4 qv = *(const float4*)(eb + (size_t)b * Dn + 4 * i16);
    float nq = qv.x * qv.x + qv.y * qv.y + qv.z * qv.z + qv.w * qv.w;
    #pragma unroll
    for (int off = 1; off < 16; off <<= 1) nq += __shfl_xor(nq, off);
    const float norm_q = sqrtf(nq);

    // 512 rows / (16 waves * 4 rows) = 8 unrolled iterations
    float maxv = 0.f;
    #pragma unroll
    for (int it = 0; it < Ln / (NW * 4); ++it) {
        const int k = it * (NW * 4) + wave * 4 + sub;
        const float4 v = *(const float4*)(eb + (size_t)k * Dn + 4 * i16);
        const float lk = lb[k];        // 4 addrs/wave -> one 16 B transaction
        float d = qv.x * v.x + qv.y * v.y + qv.z * v.z + qv.w * v.w;
        float n = v.x * v.x + v.y * v.y + v.z * v.z + v.w * v.w;
        #pragma unroll
        for (int off = 1; off < 16; off <<= 1) {
            d += __shfl_xor(d, off);
            n += __shfl_xor(n, off);
        }
        float denom = fmaxf(norm_q * sqrtf(n), EPS_COS);
        float m     = fmaxf(__fdividef(d, denom), 0.f) * lk;  // relu, mask
        maxv = fmaxf(maxv, m);
    }
    maxv = fmaxf(maxv, __shfl_xor(maxv, 16));
    maxv = fmaxf(maxv, __shfl_xor(maxv, 32));

    // prob sums: pos = sum labels*log(p+eps); lng = sum log(1-(p+eps))
    float pos = 0.f, lng = 0.f;
    if (tid < Ln) {
        float p = pb[tid] + EPS_LOG;
        pos = lb[tid] * __logf(p);
        lng = __logf(1.f - p);
    }
    #pragma unroll
    for (int off = 32; off; off >>= 1) {
        pos += __shfl_xor(pos, off);
        lng += __shfl_xor(lng, off);
    }

    __shared__ float s_max[NW], s_pos[NW], s_lng[NW];
    if (lane == 0) { s_max[wave] = maxv; s_pos[wave] = pos; s_lng[wave] = lng; }
    __syncthreads();

    if (tid == 0) {
        float rm = 0.f, P = 0.f, LN = 0.f;
        #pragma unroll
        for (int w = 0; w < NW; ++w) {
            rm = fmaxf(rm, s_max[w]);
            P += s_pos[w];
            LN += s_lng[w];
        }
        float wnl = (lb[b] == 0.f) ? rm : 0.f;   // gate on labels[b,b]
        ws[b] = -P - wnl * LN;                   // plain store, no atomics
    }
}

// K2: one wave sums the 256 per-sample partials and writes the scalar.
__global__ __launch_bounds__(64) void wnl_final(
    const float* __restrict__ ws,
    float* __restrict__ out)
{
    const int lane = threadIdx.x;                // 0..63
    const float4 v = ((const float4*)ws)[lane];  // 64 lanes x 4 = 256 floats
    float t = v.x + v.y + v.z + v.w;
    #pragma unroll
    for (int off = 32; off; off >>= 1) t += __shfl_xor(t, off);
    if (lane == 0) out[0] = t * (1.f / (float)Bn);
}

extern "C" void kernel_launch(void* const* d_in, const int* in_sizes, int n_in,
                              void* d_out, int out_size, void* d_ws, size_t ws_size,
                              hipStream_t stream) {
    const float* emb    = (const float*)d_in[0];
    const float* probs  = (const float*)d_in[1];
    const float* labels = (const float*)d_in[2];
    float* ws  = (float*)d_ws;
    float* out = (float*)d_out;

    wnl_part<<<Bn, 1024, 0, stream>>>(emb, probs, labels, ws);
    wnl_final<<<1, 64, 0, stream>>>(ws, out);
}